// Round 15
// baseline (140.560 us; speedup 1.0000x reference)
//
#include <hip/hip_runtime.h>

#define NUM_USERS 100000
#define NUM_ITEMS 50000
#define N_NODES   150000   // NUM_USERS + NUM_ITEMS
#define DIM       64
#define NNZ       1000000
#define BATCH     4096

#define BROWS  240                    // rows per bucket (625 * 240 == 150000)
#define NBUCK  (N_NODES / BROWS)      // 625
#define WPB    (BROWS / 8)            // 30 waves per bucket
#define NWG    256                    // workgroups in count/scatter
#define CHUNK  ((NNZ + NWG - 1) / NWG)// 3907 edges per WG
#define SCAN_N (NBUCK * NWG)          // 160000
#define SCAN_B 512
#define NBLK_S ((SCAN_N + SCAN_B - 1) / SCAN_B)  // 313
#define MARKB  ((2 * BATCH + SCAN_B - 1) / SCAN_B)  // 16 marking blocks

#define NWAVES (NBUCK * WPB)          // 18750 spmm waves
#define NBINS  32                     // degree bins for bucket-local sort
#define ESCAP  4096                   // LDS edge cap per bucket (mean 1600)
#define PACKED_CAP  2500000           // padded edge slots, full packing
#define PACKED2_CAP 1500000           // padded edge slots, flagged subset
#define CVB    2048                   // convert blocks inside fat kernel
#define BMW    4704                   // bitmap words (150000/32 rounded up)

typedef unsigned int uint32;

// bf16 helpers (RNE convert, cheap expand)
__device__ __forceinline__ ushort f2bf(float f) {
    uint32 u = __float_as_uint(f);
    u += 0x7FFFu + ((u >> 16) & 1u);
    return (ushort)(u >> 16);
}
__device__ __forceinline__ float bf2f(ushort u) {
    return __uint_as_float(((uint32)u) << 16);
}

// ---------------------------------------------------------------------------
// fat kernel: [0,NWG) bucket histogram; [NWG,NWG+CVB) fp32->bf16 convert;
// last block zeroes the two row bitmaps.
// ---------------------------------------------------------------------------
__global__ __launch_bounds__(256) void count_convert_kernel(
        const int* __restrict__ rows,
        int* __restrict__ cntArr,
        const float* __restrict__ user_emb,
        const float* __restrict__ item_emb,
        ushort* __restrict__ xb,
        uint32* __restrict__ bbm,
        uint32* __restrict__ fbm) {
    __shared__ int h[NBUCK];
    if (blockIdx.x < NWG) {
        for (int k = threadIdx.x; k < NBUCK; k += 256) h[k] = 0;
        __syncthreads();
        int lo = blockIdx.x * CHUNK, hi = min(NNZ, lo + CHUNK);
        for (int e = lo + threadIdx.x; e < hi; e += 256)
            atomicAdd(&h[__builtin_nontemporal_load(&rows[e]) / BROWS], 1);
        __syncthreads();
        for (int k = threadIdx.x; k < NBUCK; k += 256)
            cntArr[k * NWG + blockIdx.x] = h[k];
    } else if (blockIdx.x < NWG + CVB) {
        const int64_t total4 = (int64_t)N_NODES * DIM / 4;
        const int64_t user4  = (int64_t)NUM_USERS * DIM / 4;
        int64_t stride = (int64_t)CVB * 256;
        for (int64_t i = (int64_t)(blockIdx.x - NWG) * 256 + threadIdx.x;
             i < total4; i += stride) {
            float4 v = (i < user4) ? ((const float4*)user_emb)[i]
                                   : ((const float4*)item_emb)[i - user4];
            ushort4 o;
            o.x = f2bf(v.x); o.y = f2bf(v.y); o.z = f2bf(v.z); o.w = f2bf(v.w);
            ((ushort4*)xb)[i] = o;
        }
    } else {
        for (int k = threadIdx.x; k < BMW; k += 256) { bbm[k] = 0; fbm[k] = 0; }
    }
}

// ---------------------------------------------------------------------------
// scan A: per-block exclusive scan (baseArr BLOCK-LOCAL; consumers add
// blksum[idx>>9] inline). Extra blocks mark the batch-row bitmap.
// ---------------------------------------------------------------------------
__global__ __launch_bounds__(SCAN_B) void scan_block_kernel(
        const int* __restrict__ in, int* __restrict__ out,
        int* __restrict__ blksum, int n,
        const int* __restrict__ user_idx, const int* __restrict__ item_idx,
        uint32* __restrict__ bbm) {
    if (blockIdx.x >= NBLK_S) {
        int i = (int)(blockIdx.x - NBLK_S) * SCAN_B + threadIdx.x;
        if (i < 2 * BATCH) {
            int row = (i < BATCH) ? user_idx[i] : (NUM_USERS + item_idx[i - BATCH]);
            atomicOr(&bbm[row >> 5], 1u << (row & 31));
        }
        return;
    }
    __shared__ int sh[SCAN_B];
    int i = blockIdx.x * SCAN_B + threadIdx.x;
    int v = (i < n) ? in[i] : 0;
    sh[threadIdx.x] = v;
    __syncthreads();
    for (int off = 1; off < SCAN_B; off <<= 1) {
        int t = (threadIdx.x >= off) ? sh[threadIdx.x - off] : 0;
        __syncthreads();
        sh[threadIdx.x] += t;
        __syncthreads();
    }
    if (i < n) out[i] = sh[threadIdx.x] - v;
    if (threadIdx.x == SCAN_B - 1) blksum[blockIdx.x] = sh[SCAN_B - 1];
}

// ---------------------------------------------------------------------------
// scan B: single-block exclusive scan of block sums; init rowptr[N]=NNZ,
// packed cursors gcur[0..2]=0, gcur[3]=NWAVES (full wave count)
// ---------------------------------------------------------------------------
__global__ __launch_bounds__(SCAN_B) void scan_top_kernel(int* __restrict__ blksum,
                                                          int nblk,
                                                          int* __restrict__ rowptr,
                                                          int* __restrict__ gcur) {
    __shared__ int sh[SCAN_B];
    int v = (threadIdx.x < nblk) ? blksum[threadIdx.x] : 0;
    sh[threadIdx.x] = v;
    __syncthreads();
    for (int off = 1; off < SCAN_B; off <<= 1) {
        int t = (threadIdx.x >= off) ? sh[threadIdx.x - off] : 0;
        __syncthreads();
        sh[threadIdx.x] += t;
        __syncthreads();
    }
    if (threadIdx.x < nblk) blksum[threadIdx.x] = sh[threadIdx.x] - v;
    if (threadIdx.x == 0) {
        rowptr[N_NODES] = NNZ;
        gcur[0] = 0; gcur[1] = 0; gcur[2] = 0; gcur[3] = NWAVES;
    }
}

// ---------------------------------------------------------------------------
// scatter: bucket-grouped ebuf via LDS cursors; also marks N1 (cols of
// batch-row edges) into fbm. payload: w0 = (row8 << 18) | col
// ---------------------------------------------------------------------------
__global__ __launch_bounds__(256) void scatter_lds_kernel(
        const int* __restrict__ rows,
        const int* __restrict__ cols,
        const float* __restrict__ vals,
        const int* __restrict__ baseArr,
        const int* __restrict__ blksum,
        const uint32* __restrict__ bbm,
        uint32* __restrict__ fbm,
        int2* __restrict__ ebuf) {
    __shared__ int cur[NBUCK];
    for (int k = threadIdx.x; k < NBUCK; k += 256) {
        int idx = k * NWG + blockIdx.x;
        cur[k] = baseArr[idx] + blksum[idx >> 9];   // SCAN_B == 512
    }
    __syncthreads();
    int lo = blockIdx.x * CHUNK, hi = min(NNZ, lo + CHUNK);
    for (int e = lo + threadIdx.x; e < hi; e += 256) {
        int   r = __builtin_nontemporal_load(&rows[e]);
        int   c = __builtin_nontemporal_load(&cols[e]);
        float v = __builtin_nontemporal_load(&vals[e]);
        if ((bbm[r >> 5] >> (r & 31)) & 1u)          // row in batch -> col in N1
            atomicOr(&fbm[c >> 5], 1u << (c & 31));
        int   b = r / BROWS;
        int pos = atomicAdd(&cur[b], 1);
        ebuf[pos] = make_int2(((r - b * BROWS) << 18) | c, __float_as_int(v));
    }
}

// ---------------------------------------------------------------------------
// buildpack: ONE WG per bucket. Produces (a) exact CSR + full degree-sorted
// wave packing (perm/tw/twb/packed) and (b) a SECOND packing restricted to
// flagged rows F = batch ∪ N1 (perm2/tw2/twb2/packed2) for the pruned
// layer-2 SpMM. Pad slots use scratch row N_NODES. Bucket-local in LDS;
// three global atomicAdd reservations per bucket.
// ---------------------------------------------------------------------------
__global__ __launch_bounds__(256) void buildpack_kernel(
        const int* __restrict__ baseArr,
        const int* __restrict__ blksum,
        const int2* __restrict__ ebuf,
        int2* __restrict__ ebuf2,
        int* __restrict__ rowptr,
        int* __restrict__ perm,
        int* __restrict__ tw,
        int* __restrict__ twb,
        int2* __restrict__ packed,
        const uint32* __restrict__ bbm,
        const uint32* __restrict__ fbm,
        int* __restrict__ perm2,
        int* __restrict__ tw2,
        int* __restrict__ twb2,
        int2* __restrict__ packed2,
        int* __restrict__ gcur) {
    __shared__ int  cnt[BROWS];
    __shared__ int  rowofs[BROWS];
    __shared__ int  cur[BROWS];      // reused as flag[] in phase B
    __shared__ int  sh[256];
    __shared__ int2 es[ESCAP];
    __shared__ int  sr[BROWS];
    __shared__ int  sr2[BROWS];
    __shared__ int  binc[NBINS];
    __shared__ int  binb[NBINS];
    __shared__ int  twq[WPB];        // reused for subset in phase B
    __shared__ int  lofs[WPB];
    __shared__ int  baseSh, nfSh, baseW2, baseS2;

    const int b   = blockIdx.x;
    const int tid = threadIdx.x;
    const int i0  = b * NWG;
    const int start = baseArr[i0] + blksum[i0 >> 9];
    const int i1  = (b + 1) * NWG;
    const int end = (b == NBUCK - 1) ? NNZ : (baseArr[i1] + blksum[i1 >> 9]);
    const int m   = end - start;

    for (int k = tid; k < BROWS; k += 256) cnt[k] = 0;
    if (tid < NBINS) binc[tid] = 0;
    __syncthreads();

    // 1. degree count
    for (int e = start + tid; e < end; e += 256)
        atomicAdd(&cnt[ebuf[e].x >> 18], 1);
    __syncthreads();

    // scan cnt -> rowofs; rowptr global
    int v = (tid < BROWS) ? cnt[tid] : 0;
    sh[tid] = v;
    __syncthreads();
    for (int off = 1; off < 256; off <<= 1) {
        int t = (tid >= off) ? sh[tid - off] : 0;
        __syncthreads();
        sh[tid] += t;
        __syncthreads();
    }
    if (tid < BROWS) {
        int p = sh[tid] - v;
        rowofs[tid] = p;
        cur[tid] = p;
        rowptr[b * BROWS + tid] = start + p;
    }
    __syncthreads();

    // 2. row-sort edges into LDS; mirror to ebuf2
    for (int e = start + tid; e < end; e += 256) {
        int2 p = ebuf[e];
        int row8 = p.x >> 18;
        int col  = p.x & 0x3FFFF;
        int pos = atomicAdd(&cur[row8], 1);
        if (pos < ESCAP) es[pos] = make_int2(col, p.y);
    }
    __syncthreads();
    for (int k = tid; k < m; k += 256) ebuf2[start + k] = es[k];

    // 3. counting sort of rows by degree -> sr
    if (tid < BROWS) atomicAdd(&binc[min(cnt[tid], NBINS - 1)], 1);
    __syncthreads();
    if (tid == 0) {
        int s = 0;
        for (int k = 0; k < NBINS; ++k) { binb[k] = s; s += binc[k]; binc[k] = 0; }
    }
    __syncthreads();
    if (tid < BROWS) {
        int bin = min(cnt[tid], NBINS - 1);
        int idx = atomicAdd(&binc[bin], 1);
        sr[binb[bin] + idx] = tid;
    }
    __syncthreads();

    // 4. full packing: per-wave max degree; serial scan; reserve
    if (tid < WPB) {
        int T = 0;
        #pragma unroll
        for (int j = 0; j < 8; ++j) T = max(T, cnt[sr[8 * tid + j]]);
        twq[tid] = T;
    }
    __syncthreads();
    if (tid == 0) {
        int s = 0;
        for (int q = 0; q < WPB; ++q) { lofs[q] = s; s += twq[q]; }
        baseSh = atomicAdd(&gcur[0], s);
    }
    __syncthreads();
    const int base = baseSh;

    if (tid < WPB) {
        tw[b * WPB + tid]  = twq[tid];
        twb[b * WPB + tid] = base + lofs[tid];
    }
    if (tid < BROWS) perm[b * BROWS + tid] = b * BROWS + sr[tid];

    for (int q = 0; q < WPB; ++q) {
        int T = twq[q];
        int64_t bq = (int64_t)(base + lofs[q]) * 8;
        for (int idx = tid; idx < 8 * T; idx += 256) {
            int t = idx >> 3, j = idx & 7;
            int row8 = sr[8 * q + j];
            int d = cnt[row8];
            int2 ed = (t < d) ? es[rowofs[row8] + t] : make_int2(0, 0);
            packed[bq + idx] = ed;
        }
    }
    __syncthreads();

    // ---- phase B: flagged-subset packing for layer 2 ----
    // flag per local row (reuse cur[])
    if (tid < BROWS) {
        int row = b * BROWS + tid;
        cur[tid] = (int)(((bbm[row >> 5] | fbm[row >> 5]) >> (row & 31)) & 1u);
    }
    __syncthreads();
    // compact sr (degree-sorted order) to sr2
    int v2 = (tid < BROWS) ? cur[sr[tid]] : 0;
    sh[tid] = v2;
    __syncthreads();
    for (int off = 1; off < 256; off <<= 1) {
        int t = (tid >= off) ? sh[tid - off] : 0;
        __syncthreads();
        sh[tid] += t;
        __syncthreads();
    }
    if (tid < BROWS && v2) sr2[sh[tid] - 1] = sr[tid];
    if (tid == 255) nfSh = sh[255];
    __syncthreads();
    const int nf = nfSh;
    const int nwav2 = (nf + 7) >> 3;

    if (tid < nwav2) {
        int T = 0;
        #pragma unroll
        for (int j = 0; j < 8; ++j) {
            int s = 8 * tid + j;
            if (s < nf) T = max(T, cnt[sr2[s]]);
        }
        twq[tid] = T;      // reuse
    }
    __syncthreads();
    if (tid == 0) {
        int s = 0;
        for (int q = 0; q < nwav2; ++q) { lofs[q] = s; s += twq[q]; }
        baseW2 = nwav2 ? atomicAdd(&gcur[2], nwav2) : 0;
        baseS2 = s     ? atomicAdd(&gcur[1], s)     : 0;
    }
    __syncthreads();
    if (tid < nwav2) {
        tw2[baseW2 + tid]  = twq[tid];
        twb2[baseW2 + tid] = baseS2 + lofs[tid];
    }
    if (tid < 8 * nwav2) {
        int s = tid;
        perm2[(int64_t)(baseW2 + (s >> 3)) * 8 + (s & 7)] =
            (s < nf) ? b * BROWS + sr2[s] : N_NODES;   // pad -> scratch row
    }
    for (int q = 0; q < nwav2; ++q) {
        int T = twq[q];
        int64_t bq = (int64_t)(baseS2 + lofs[q]) * 8;
        for (int idx = tid; idx < 8 * T; idx += 256) {
            int t = idx >> 3, j = idx & 7;
            int s = 8 * q + j;
            int2 ed = make_int2(0, 0);
            if (s < nf) {
                int row8 = sr2[s];
                int d = cnt[row8];
                if (t < d) ed = es[rowofs[row8] + t];
            }
            packed2[bq + idx] = ed;
        }
    }
}

// ---------------------------------------------------------------------------
// SpMM packed: wave w -> 8 perm rows (w < *nwave; device-side count).
// Per 8-trip group: ONE coalesced 512B nontemporal edge load; per trip:
// 2 shfl broadcasts + ONE uint4 gather + 8 unpack/FMA.
// ---------------------------------------------------------------------------
__global__ __launch_bounds__(256) void spmm8p_kernel(
        const int* __restrict__ perm,
        const int* __restrict__ twb,
        const int* __restrict__ tw,
        const long long* __restrict__ packed,
        const ushort* __restrict__ xin,
        ushort* __restrict__ yout,
        const int* __restrict__ nwave) {
    int w = (int)((blockIdx.x * blockDim.x + threadIdx.x) >> 6);
    if (w >= nwave[0]) return;
    const int lane = threadIdx.x & 63;
    const int j    = lane >> 3;          // row slot 0..7
    const int sub8 = lane & 7;           // dim chunk (8 bf16)
    const int T = tw[w];
    const int64_t base = (int64_t)twb[w] * 8;
    const int rowv = perm[8 * w + j];
    const uint4* __restrict__ x4 = (const uint4*)xin;

    float acc[8] = {0.f, 0.f, 0.f, 0.f, 0.f, 0.f, 0.f, 0.f};

    #define DO_TRIP(tt)                                                        \
    {                                                                          \
        int   colsel = __shfl(edc, (tt) * 8 + j, 64);                          \
        float valsel = __uint_as_float((uint32)__shfl(edv, (tt) * 8 + j, 64)); \
        uint4 u = x4[(uint32)colsel * 8 + sub8];                               \
        acc[0] = fmaf(valsel, __uint_as_float(u.x << 16), acc[0]);             \
        acc[1] = fmaf(valsel, __uint_as_float(u.x & 0xFFFF0000u), acc[1]);     \
        acc[2] = fmaf(valsel, __uint_as_float(u.y << 16), acc[2]);             \
        acc[3] = fmaf(valsel, __uint_as_float(u.y & 0xFFFF0000u), acc[3]);     \
        acc[4] = fmaf(valsel, __uint_as_float(u.z << 16), acc[4]);             \
        acc[5] = fmaf(valsel, __uint_as_float(u.z & 0xFFFF0000u), acc[5]);     \
        acc[6] = fmaf(valsel, __uint_as_float(u.w << 16), acc[6]);             \
        acc[7] = fmaf(valsel, __uint_as_float(u.w & 0xFFFF0000u), acc[7]);     \
    }

    int t0 = 0;
    for (; t0 + 8 <= T; t0 += 8) {       // full groups, unrolled
        long long raw = __builtin_nontemporal_load(&packed[base + (int64_t)t0 * 8 + lane]);
        int edc = (int)(uint32)(raw & 0xFFFFFFFFll);
        int edv = (int)(uint32)(raw >> 32);
        DO_TRIP(0) DO_TRIP(1) DO_TRIP(2) DO_TRIP(3)
        DO_TRIP(4) DO_TRIP(5) DO_TRIP(6) DO_TRIP(7)
    }
    if (t0 < T) {                        // tail group (wave-uniform bound)
        long long raw = __builtin_nontemporal_load(&packed[base + (int64_t)t0 * 8 + lane]);
        int edc = (int)(uint32)(raw & 0xFFFFFFFFll);
        int edv = (int)(uint32)(raw >> 32);
        int rem = T - t0;
        for (int tt = 0; tt < rem; ++tt) DO_TRIP(tt)
    }
    #undef DO_TRIP

    uint4 o;
    o.x = (uint32)f2bf(acc[0]) | ((uint32)f2bf(acc[1]) << 16);
    o.y = (uint32)f2bf(acc[2]) | ((uint32)f2bf(acc[3]) << 16);
    o.z = (uint32)f2bf(acc[4]) | ((uint32)f2bf(acc[5]) << 16);
    o.w = (uint32)f2bf(acc[6]) | ((uint32)f2bf(acc[7]) << 16);
    ((uint4*)yout)[(uint32)rowv * 8 + sub8] = o;
}

// ---------------------------------------------------------------------------
// Fused layer-3 SpMM + output epilogue (4 user + 4 item slots per wave).
// ---------------------------------------------------------------------------
__global__ __launch_bounds__(256) void batch_out_kernel(
        const int* __restrict__ user_idx,
        const int* __restrict__ item_idx,
        const int* __restrict__ rowptr,
        const int2* __restrict__ edges,
        const ushort* __restrict__ xin,
        const float* __restrict__ user_emb,
        const float* __restrict__ item_emb,
        const ushort* __restrict__ l1,
        const ushort* __restrict__ l2,
        float* __restrict__ out) {
    const int lane = threadIdx.x & 63;
    const int w = (int)(((uint32)blockIdx.x * blockDim.x + threadIdx.x) >> 6);
    const int i0 = w * 4;
    if (i0 >= BATCH) return;

    int rowv[8];
    int e[8], end[8];
    int trips = 0;
    #pragma unroll
    for (int j = 0; j < 8; ++j) {
        int row = (j < 4) ? user_idx[i0 + j]
                          : (NUM_USERS + item_idx[i0 + j - 4]);
        rowv[j] = row;
        e[j]   = rowptr[row];
        end[j] = rowptr[row + 1];
        trips = max(trips, end[j] - e[j]);
    }
    float a[8] = {0.f, 0.f, 0.f, 0.f, 0.f, 0.f, 0.f, 0.f};

    for (int t = 0; t < trips; ++t) {
        int   col[8];
        float val[8];
        #pragma unroll
        for (int j = 0; j < 8; ++j) {
            bool act = e[j] < end[j];
            int idx  = __builtin_amdgcn_readfirstlane(act ? e[j] : 0);
            int2 ed  = edges[idx];
            col[j] = __builtin_amdgcn_readfirstlane(ed.x);
            val[j] = act ? __int_as_float(ed.y) : 0.f;
            e[j]  += act ? 1 : 0;
        }
        #pragma unroll
        for (int j = 0; j < 8; ++j) {
            float xv = bf2f(xin[(int64_t)col[j] * DIM + lane]);
            a[j] = fmaf(val[j], xv, a[j]);
        }
    }

    float uvv[8];
    #pragma unroll
    for (int j = 0; j < 8; ++j) {
        int row = rowv[j];
        int64_t ro = (int64_t)row * DIM + lane;
        float emb = (j < 4) ? user_emb[ro]
                            : item_emb[(int64_t)(row - NUM_USERS) * DIM + lane];
        uvv[j] = (emb + bf2f(l1[ro]) + bf2f(l2[ro]) + a[j]) * 0.25f;
    }
    #pragma unroll
    for (int j = 0; j < 4; ++j)
        out[(int64_t)BATCH + (int64_t)(i0 + j) * DIM + lane] = uvv[j];
    #pragma unroll
    for (int j = 4; j < 8; ++j)
        out[(int64_t)BATCH + (int64_t)BATCH * DIM
            + (int64_t)(i0 + j - 4) * DIM + lane] = uvv[j];

    #pragma unroll
    for (int k = 0; k < 4; ++k) {
        float p = uvv[k] * uvv[k + 4];
        #pragma unroll
        for (int off = 32; off >= 1; off >>= 1) p += __shfl_down(p, off, 64);
        if (lane == 0) out[i0 + k] = p;
    }
}

// ---------------------------------------------------------------------------
extern "C" void kernel_launch(void* const* d_in, const int* in_sizes, int n_in,
                              void* d_out, int out_size, void* d_ws, size_t ws_size,
                              hipStream_t stream) {
    const int*   user_idx = (const int*)  d_in[0];
    const int*   item_idx = (const int*)  d_in[1];
    const int*   rows     = (const int*)  d_in[2];
    const int*   cols     = (const int*)  d_in[3];
    const float* vals     = (const float*)d_in[4];
    const float* user_emb = (const float*)d_in[5];
    const float* item_emb = (const float*)d_in[6];
    float*       out      = (float*)d_out;

    // ---- workspace layout ----
    char* base = (char*)d_ws;
    size_t off = 0;
    auto alloc = [&](size_t bytes) -> char* {
        char* p = base + off;
        off = (off + bytes + 255) & ~(size_t)255;
        return p;
    };
    int*    cntArr  = (int*)   alloc((size_t)SCAN_N * sizeof(int));
    int*    baseArr = (int*)   alloc((size_t)SCAN_N * sizeof(int));
    int*    blksum  = (int*)   alloc((size_t)(NBLK_S + 1) * sizeof(int));
    int*    rowptr  = (int*)   alloc((size_t)(N_NODES + 1) * sizeof(int));
    int*    gcur    = (int*)   alloc((size_t)64 * sizeof(int));
    uint32* bbm     = (uint32*)alloc((size_t)BMW * sizeof(uint32));
    uint32* fbm     = (uint32*)alloc((size_t)BMW * sizeof(uint32));
    int2*   ebuf    = (int2*)  alloc((size_t)NNZ * sizeof(int2));
    int2*   ebuf2   = (int2*)  alloc((size_t)NNZ * sizeof(int2));
    int2*   packed  = (int2*)  alloc((size_t)PACKED_CAP * sizeof(int2));
    int2*   packed2 = (int2*)  alloc((size_t)PACKED2_CAP * sizeof(int2));
    int*    perm    = (int*)   alloc((size_t)N_NODES * sizeof(int));
    int*    perm2   = (int*)   alloc((size_t)N_NODES * sizeof(int));
    int*    tw      = (int*)   alloc((size_t)NWAVES * sizeof(int));
    int*    twb     = (int*)   alloc((size_t)NWAVES * sizeof(int));
    int*    tw2     = (int*)   alloc((size_t)NWAVES * sizeof(int));
    int*    twb2    = (int*)   alloc((size_t)NWAVES * sizeof(int));
    ushort* xb      = (ushort*)alloc((size_t)N_NODES * DIM * sizeof(ushort));
    ushort* buf0    = (ushort*)alloc((size_t)N_NODES * DIM * sizeof(ushort));
    ushort* buf1    = (ushort*)alloc((size_t)(N_NODES + 8) * DIM * sizeof(ushort));

    const int TB = 256;

    // ---- count + convert + bitmap zero (fused independent work) ----
    count_convert_kernel<<<NWG + CVB + 1, TB, 0, stream>>>(
        rows, cntArr, user_emb, item_emb, xb, bbm, fbm);

    // ---- scan + batch-bitmap marking ----
    scan_block_kernel<<<NBLK_S + MARKB, SCAN_B, 0, stream>>>(
        cntArr, baseArr, blksum, SCAN_N, user_idx, item_idx, bbm);
    scan_top_kernel<<<1, SCAN_B, 0, stream>>>(blksum, NBLK_S, rowptr, gcur);

    // ---- scatter (+ N1 marking) + buildpack (full + flagged packings) ----
    scatter_lds_kernel<<<NWG, TB, 0, stream>>>(
        rows, cols, vals, baseArr, blksum, bbm, fbm, ebuf);
    buildpack_kernel<<<NBUCK, TB, 0, stream>>>(
        baseArr, blksum, ebuf, ebuf2, rowptr, perm, tw, twb, packed,
        bbm, fbm, perm2, tw2, twb2, packed2, gcur);

    // ---- propagation ----
    const int spmmBlocks = (NWAVES * 64 + TB - 1) / TB;
    // layer 1: full (wave count = gcur[3] = NWAVES)
    spmm8p_kernel<<<spmmBlocks, TB, 0, stream>>>(
        perm, twb, tw, (const long long*)packed, xb, buf0, gcur + 3);
    // layer 2: flagged subset only (wave count = gcur[2])
    spmm8p_kernel<<<spmmBlocks, TB, 0, stream>>>(
        perm2, twb2, tw2, (const long long*)packed2, buf0, buf1, gcur + 2);

    // ---- fused layer-3 + output ----
    const int boBlocks = (BATCH / 4 * 64 + TB - 1) / TB;
    batch_out_kernel<<<boBlocks, TB, 0, stream>>>(
        user_idx, item_idx, rowptr, ebuf2, buf1,
        user_emb, item_emb, buf0, buf1, out);
}

// Round 16
// 127.132 us; speedup vs baseline: 1.1056x; 1.1056x over previous
//
#include <hip/hip_runtime.h>

#define NUM_USERS 100000
#define NUM_ITEMS 50000
#define N_NODES   150000   // NUM_USERS + NUM_ITEMS
#define DIM       64
#define NNZ       1000000
#define BATCH     4096

#define BROWS  240                    // rows per bucket (625 * 240 == 150000)
#define NBUCK  (N_NODES / BROWS)      // 625
#define WPB    (BROWS / 8)            // 30 waves per bucket
#define NWG    256                    // workgroups in count/scatter
#define CHUNK  ((NNZ + NWG - 1) / NWG)// 3907 edges per WG
#define SCAN_N (NBUCK * NWG)          // 160000
#define SCAN_B 512
#define NBLK_S ((SCAN_N + SCAN_B - 1) / SCAN_B)  // 313

#define NWAVES (NBUCK * WPB)          // 18750 spmm waves
#define NBINS  32                     // degree bins for bucket-local sort
#define ESCAP  4096                   // LDS edge cap per bucket (mean 1600)
#define PACKED_CAP 3000000            // padded edge slots (worst ~1.2M expected)
#define CVB    2048                   // convert blocks inside fat kernel

typedef unsigned int uint32;

// bf16 helpers (RNE convert, cheap expand)
__device__ __forceinline__ ushort f2bf(float f) {
    uint32 u = __float_as_uint(f);
    u += 0x7FFFu + ((u >> 16) & 1u);
    return (ushort)(u >> 16);
}
__device__ __forceinline__ float bf2f(ushort u) {
    return __uint_as_float(((uint32)u) << 16);
}

// ---------------------------------------------------------------------------
// fat kernel: blocks [0,NWG) = bucket-occupancy histogram (bucket-major);
// blocks [NWG, NWG+CVB) = fp32->bf16 feature convert. Independent work
// merged to cut one graph dispatch.
// ---------------------------------------------------------------------------
__global__ __launch_bounds__(256) void count_convert_kernel(
        const int* __restrict__ rows,
        int* __restrict__ cntArr,
        const float* __restrict__ user_emb,
        const float* __restrict__ item_emb,
        ushort* __restrict__ xb) {
    __shared__ int h[NBUCK];
    if (blockIdx.x < NWG) {
        for (int k = threadIdx.x; k < NBUCK; k += 256) h[k] = 0;
        __syncthreads();
        int lo = blockIdx.x * CHUNK, hi = min(NNZ, lo + CHUNK);
        for (int e = lo + threadIdx.x; e < hi; e += 256)
            atomicAdd(&h[__builtin_nontemporal_load(&rows[e]) / BROWS], 1);
        __syncthreads();
        for (int k = threadIdx.x; k < NBUCK; k += 256)
            cntArr[k * NWG + blockIdx.x] = h[k];
    } else {
        const int64_t total4 = (int64_t)N_NODES * DIM / 4;
        const int64_t user4  = (int64_t)NUM_USERS * DIM / 4;
        int64_t stride = (int64_t)CVB * 256;
        for (int64_t i = (int64_t)(blockIdx.x - NWG) * 256 + threadIdx.x;
             i < total4; i += stride) {
            float4 v = (i < user4) ? ((const float4*)user_emb)[i]
                                   : ((const float4*)item_emb)[i - user4];
            ushort4 o;
            o.x = f2bf(v.x); o.y = f2bf(v.y); o.z = f2bf(v.z); o.w = f2bf(v.w);
            ((ushort4*)xb)[i] = o;
        }
    }
}

// ---------------------------------------------------------------------------
// scan A: per-block exclusive scan; blksum <- block total
// (baseArr stays BLOCK-LOCAL; consumers add blksum[idx>>9] inline)
// ---------------------------------------------------------------------------
__global__ __launch_bounds__(SCAN_B) void scan_block_kernel(
        const int* __restrict__ in, int* __restrict__ out,
        int* __restrict__ blksum, int n) {
    __shared__ int sh[SCAN_B];
    int i = blockIdx.x * SCAN_B + threadIdx.x;
    int v = (i < n) ? in[i] : 0;
    sh[threadIdx.x] = v;
    __syncthreads();
    for (int off = 1; off < SCAN_B; off <<= 1) {
        int t = (threadIdx.x >= off) ? sh[threadIdx.x - off] : 0;
        __syncthreads();
        sh[threadIdx.x] += t;
        __syncthreads();
    }
    if (i < n) out[i] = sh[threadIdx.x] - v;
    if (threadIdx.x == SCAN_B - 1) blksum[blockIdx.x] = sh[SCAN_B - 1];
}

// ---------------------------------------------------------------------------
// scan B: single-block exclusive scan of block sums; also init
// rowptr[N_NODES]=NNZ and the packed-region cursor (folds old scan_fix)
// ---------------------------------------------------------------------------
__global__ __launch_bounds__(SCAN_B) void scan_top_kernel(int* __restrict__ blksum,
                                                          int nblk,
                                                          int* __restrict__ rowptr,
                                                          int* __restrict__ gcur) {
    __shared__ int sh[SCAN_B];
    int v = (threadIdx.x < nblk) ? blksum[threadIdx.x] : 0;
    sh[threadIdx.x] = v;
    __syncthreads();
    for (int off = 1; off < SCAN_B; off <<= 1) {
        int t = (threadIdx.x >= off) ? sh[threadIdx.x - off] : 0;
        __syncthreads();
        sh[threadIdx.x] += t;
        __syncthreads();
    }
    if (threadIdx.x < nblk) blksum[threadIdx.x] = sh[threadIdx.x] - v;
    if (threadIdx.x == 0) { rowptr[N_NODES] = NNZ; gcur[0] = 0; }
}

// ---------------------------------------------------------------------------
// scatter: bucket-grouped ebuf via LDS cursors. baseArr fix (+blksum) inline.
// payload: w0 = (row8 << 18) | col
// ---------------------------------------------------------------------------
__global__ __launch_bounds__(256) void scatter_lds_kernel(
        const int* __restrict__ rows,
        const int* __restrict__ cols,
        const float* __restrict__ vals,
        const int* __restrict__ baseArr,
        const int* __restrict__ blksum,
        int2* __restrict__ ebuf) {
    __shared__ int cur[NBUCK];
    for (int k = threadIdx.x; k < NBUCK; k += 256) {
        int idx = k * NWG + blockIdx.x;
        cur[k] = baseArr[idx] + blksum[idx >> 9];   // SCAN_B == 512
    }
    __syncthreads();
    int lo = blockIdx.x * CHUNK, hi = min(NNZ, lo + CHUNK);
    for (int e = lo + threadIdx.x; e < hi; e += 256) {
        int   r = __builtin_nontemporal_load(&rows[e]);
        int   c = __builtin_nontemporal_load(&cols[e]);
        float v = __builtin_nontemporal_load(&vals[e]);
        int   b = r / BROWS;
        int pos = atomicAdd(&cur[b], 1);
        ebuf[pos] = make_int2(((r - b * BROWS) << 18) | c, __float_as_int(v));
    }
}

// ---------------------------------------------------------------------------
// buildpack: ONE WG per bucket (localsort + degree-sort + tw scan + fill),
// entirely bucket-local in LDS; one global atomicAdd per bucket.
// ---------------------------------------------------------------------------
__global__ __launch_bounds__(256) void buildpack_kernel(
        const int* __restrict__ baseArr,
        const int* __restrict__ blksum,
        const int2* __restrict__ ebuf,
        int2* __restrict__ ebuf2,
        int* __restrict__ rowptr,
        int* __restrict__ perm,
        int* __restrict__ tw,
        int* __restrict__ twb,
        int2* __restrict__ packed,
        int* __restrict__ gcur) {
    __shared__ int  cnt[BROWS];
    __shared__ int  rowofs[BROWS];
    __shared__ int  cur[BROWS];
    __shared__ int  sh[256];
    __shared__ int2 es[ESCAP];
    __shared__ int  sr[BROWS];
    __shared__ int  binc[NBINS];
    __shared__ int  binb[NBINS];
    __shared__ int  twq[WPB];
    __shared__ int  lofs[WPB];
    __shared__ int  baseSh;

    const int b   = blockIdx.x;
    const int tid = threadIdx.x;
    const int i0  = b * NWG;
    const int start = baseArr[i0] + blksum[i0 >> 9];
    const int i1  = (b + 1) * NWG;
    const int end = (b == NBUCK - 1) ? NNZ : (baseArr[i1] + blksum[i1 >> 9]);
    const int m   = end - start;

    for (int k = tid; k < BROWS; k += 256) cnt[k] = 0;
    if (tid < NBINS) binc[tid] = 0;
    __syncthreads();

    // 1. degree count
    for (int e = start + tid; e < end; e += 256)
        atomicAdd(&cnt[ebuf[e].x >> 18], 1);
    __syncthreads();

    // scan cnt -> rowofs; rowptr global
    int v = (tid < BROWS) ? cnt[tid] : 0;
    sh[tid] = v;
    __syncthreads();
    for (int off = 1; off < 256; off <<= 1) {
        int t = (tid >= off) ? sh[tid - off] : 0;
        __syncthreads();
        sh[tid] += t;
        __syncthreads();
    }
    if (tid < BROWS) {
        int p = sh[tid] - v;
        rowofs[tid] = p;
        cur[tid] = p;
        rowptr[b * BROWS + tid] = start + p;
    }
    __syncthreads();

    // 2. row-sort edges into LDS; mirror to ebuf2
    for (int e = start + tid; e < end; e += 256) {
        int2 p = ebuf[e];
        int row8 = p.x >> 18;
        int col  = p.x & 0x3FFFF;
        int pos = atomicAdd(&cur[row8], 1);
        if (pos < ESCAP) es[pos] = make_int2(col, p.y);
    }
    __syncthreads();
    for (int k = tid; k < m; k += 256) ebuf2[start + k] = es[k];

    // 3. counting sort of rows by degree
    if (tid < BROWS) atomicAdd(&binc[min(cnt[tid], NBINS - 1)], 1);
    __syncthreads();
    if (tid == 0) {
        int s = 0;
        for (int k = 0; k < NBINS; ++k) { binb[k] = s; s += binc[k]; binc[k] = 0; }
    }
    __syncthreads();
    if (tid < BROWS) {
        int bin = min(cnt[tid], NBINS - 1);
        int idx = atomicAdd(&binc[bin], 1);
        sr[binb[bin] + idx] = tid;
    }
    __syncthreads();

    // 4. per-wave max degree; serial scan; reserve packed region
    if (tid < WPB) {
        int T = 0;
        #pragma unroll
        for (int j = 0; j < 8; ++j) T = max(T, cnt[sr[8 * tid + j]]);
        twq[tid] = T;
    }
    __syncthreads();
    if (tid == 0) {
        int s = 0;
        for (int q = 0; q < WPB; ++q) { lofs[q] = s; s += twq[q]; }
        baseSh = atomicAdd(gcur, s);
    }
    __syncthreads();
    const int base = baseSh;

    // 5. outputs
    if (tid < WPB) {
        tw[b * WPB + tid]  = twq[tid];
        twb[b * WPB + tid] = base + lofs[tid];
    }
    if (tid < BROWS) perm[b * BROWS + tid] = b * BROWS + sr[tid];

    for (int q = 0; q < WPB; ++q) {
        int T = twq[q];
        int64_t bq = (int64_t)(base + lofs[q]) * 8;
        for (int idx = tid; idx < 8 * T; idx += 256) {
            int t = idx >> 3, j = idx & 7;
            int row8 = sr[8 * q + j];
            int d = cnt[row8];
            int2 ed = (t < d) ? es[rowofs[row8] + t] : make_int2(0, 0);
            packed[bq + idx] = ed;
        }
    }
}

// ---------------------------------------------------------------------------
// SpMM packed: wave w -> 8 perm rows. Per 8-trip group: ONE coalesced 512B
// NONTEMPORAL edge load (read-once stream; keep L2 for x gathers); per trip:
// 2 shfl broadcasts + ONE uint4 gather + 8 unpack/FMA.
// ---------------------------------------------------------------------------
__global__ __launch_bounds__(256) void spmm8p_kernel(
        const int* __restrict__ perm,
        const int* __restrict__ twb,
        const int* __restrict__ tw,
        const long long* __restrict__ packed,
        const ushort* __restrict__ xin,
        ushort* __restrict__ yout) {
    int w = (int)((blockIdx.x * blockDim.x + threadIdx.x) >> 6);
    if (w >= NWAVES) return;
    const int lane = threadIdx.x & 63;
    const int j    = lane >> 3;          // row slot 0..7
    const int sub8 = lane & 7;           // dim chunk (8 bf16)
    const int T = tw[w];
    const int64_t base = (int64_t)twb[w] * 8;
    const int rowv = perm[8 * w + j];
    const uint4* __restrict__ x4 = (const uint4*)xin;

    float acc[8] = {0.f, 0.f, 0.f, 0.f, 0.f, 0.f, 0.f, 0.f};

    #define DO_TRIP(tt)                                                        \
    {                                                                          \
        int   colsel = __shfl(edc, (tt) * 8 + j, 64);                          \
        float valsel = __uint_as_float((uint32)__shfl(edv, (tt) * 8 + j, 64)); \
        uint4 u = x4[(uint32)colsel * 8 + sub8];                               \
        acc[0] = fmaf(valsel, __uint_as_float(u.x << 16), acc[0]);             \
        acc[1] = fmaf(valsel, __uint_as_float(u.x & 0xFFFF0000u), acc[1]);     \
        acc[2] = fmaf(valsel, __uint_as_float(u.y << 16), acc[2]);             \
        acc[3] = fmaf(valsel, __uint_as_float(u.y & 0xFFFF0000u), acc[3]);     \
        acc[4] = fmaf(valsel, __uint_as_float(u.z << 16), acc[4]);             \
        acc[5] = fmaf(valsel, __uint_as_float(u.z & 0xFFFF0000u), acc[5]);     \
        acc[6] = fmaf(valsel, __uint_as_float(u.w << 16), acc[6]);             \
        acc[7] = fmaf(valsel, __uint_as_float(u.w & 0xFFFF0000u), acc[7]);     \
    }

    int t0 = 0;
    for (; t0 + 8 <= T; t0 += 8) {       // full groups, unrolled
        long long raw = __builtin_nontemporal_load(&packed[base + (int64_t)t0 * 8 + lane]);
        int edc = (int)(uint32)(raw & 0xFFFFFFFFll);
        int edv = (int)(uint32)(raw >> 32);
        DO_TRIP(0) DO_TRIP(1) DO_TRIP(2) DO_TRIP(3)
        DO_TRIP(4) DO_TRIP(5) DO_TRIP(6) DO_TRIP(7)
    }
    if (t0 < T) {                        // tail group (wave-uniform bound)
        long long raw = __builtin_nontemporal_load(&packed[base + (int64_t)t0 * 8 + lane]);
        int edc = (int)(uint32)(raw & 0xFFFFFFFFll);
        int edv = (int)(uint32)(raw >> 32);
        int rem = T - t0;
        for (int tt = 0; tt < rem; ++tt) DO_TRIP(tt)
    }
    #undef DO_TRIP

    uint4 o;
    o.x = (uint32)f2bf(acc[0]) | ((uint32)f2bf(acc[1]) << 16);
    o.y = (uint32)f2bf(acc[2]) | ((uint32)f2bf(acc[3]) << 16);
    o.z = (uint32)f2bf(acc[4]) | ((uint32)f2bf(acc[5]) << 16);
    o.w = (uint32)f2bf(acc[6]) | ((uint32)f2bf(acc[7]) << 16);
    ((uint4*)yout)[(uint32)rowv * 8 + sub8] = o;
}

// ---------------------------------------------------------------------------
// Fused layer-3 SpMM + output epilogue. Wave w owns 4 (user,item) batch
// pairs: slots j=0..3 -> user rows of batch i0+j, j=4..7 -> item rows of
// batch i0+(j-4). 8-chain CSR SpMM (readfirstlane MLP), then
// uv/iv = (emb + l1 + l2 + l3)/4, coalesced writes, 4 wave-reduce dots.
// ---------------------------------------------------------------------------
__global__ __launch_bounds__(256) void batch_out_kernel(
        const int* __restrict__ user_idx,
        const int* __restrict__ item_idx,
        const int* __restrict__ rowptr,
        const int2* __restrict__ edges,
        const ushort* __restrict__ xin,
        const float* __restrict__ user_emb,
        const float* __restrict__ item_emb,
        const ushort* __restrict__ l1,
        const ushort* __restrict__ l2,
        float* __restrict__ out) {
    const int lane = threadIdx.x & 63;
    const int w = (int)(((uint32)blockIdx.x * blockDim.x + threadIdx.x) >> 6);
    const int i0 = w * 4;
    if (i0 >= BATCH) return;

    int rowv[8];
    int e[8], end[8];
    int trips = 0;
    #pragma unroll
    for (int j = 0; j < 8; ++j) {
        int row = (j < 4) ? user_idx[i0 + j]
                          : (NUM_USERS + item_idx[i0 + j - 4]);
        rowv[j] = row;
        e[j]   = rowptr[row];
        end[j] = rowptr[row + 1];
        trips = max(trips, end[j] - e[j]);
    }
    float a[8] = {0.f, 0.f, 0.f, 0.f, 0.f, 0.f, 0.f, 0.f};

    for (int t = 0; t < trips; ++t) {
        int   col[8];
        float val[8];
        #pragma unroll
        for (int j = 0; j < 8; ++j) {
            bool act = e[j] < end[j];
            int idx  = __builtin_amdgcn_readfirstlane(act ? e[j] : 0);
            int2 ed  = edges[idx];
            col[j] = __builtin_amdgcn_readfirstlane(ed.x);
            val[j] = act ? __int_as_float(ed.y) : 0.f;
            e[j]  += act ? 1 : 0;
        }
        #pragma unroll
        for (int j = 0; j < 8; ++j) {
            float xv = bf2f(xin[(int64_t)col[j] * DIM + lane]);
            a[j] = fmaf(val[j], xv, a[j]);
        }
    }

    // epilogue: uv_j = (emb + l1 + l2 + l3)/4
    float uvv[8];
    #pragma unroll
    for (int j = 0; j < 8; ++j) {
        int row = rowv[j];
        int64_t ro = (int64_t)row * DIM + lane;
        float emb = (j < 4) ? user_emb[ro]
                            : item_emb[(int64_t)(row - NUM_USERS) * DIM + lane];
        uvv[j] = (emb + bf2f(l1[ro]) + bf2f(l2[ro]) + a[j]) * 0.25f;
    }
    #pragma unroll
    for (int j = 0; j < 4; ++j)
        out[(int64_t)BATCH + (int64_t)(i0 + j) * DIM + lane] = uvv[j];
    #pragma unroll
    for (int j = 4; j < 8; ++j)
        out[(int64_t)BATCH + (int64_t)BATCH * DIM
            + (int64_t)(i0 + j - 4) * DIM + lane] = uvv[j];

    #pragma unroll
    for (int k = 0; k < 4; ++k) {
        float p = uvv[k] * uvv[k + 4];
        #pragma unroll
        for (int off = 32; off >= 1; off >>= 1) p += __shfl_down(p, off, 64);
        if (lane == 0) out[i0 + k] = p;
    }
}

// ---------------------------------------------------------------------------
extern "C" void kernel_launch(void* const* d_in, const int* in_sizes, int n_in,
                              void* d_out, int out_size, void* d_ws, size_t ws_size,
                              hipStream_t stream) {
    const int*   user_idx = (const int*)  d_in[0];
    const int*   item_idx = (const int*)  d_in[1];
    const int*   rows     = (const int*)  d_in[2];
    const int*   cols     = (const int*)  d_in[3];
    const float* vals     = (const float*)d_in[4];
    const float* user_emb = (const float*)d_in[5];
    const float* item_emb = (const float*)d_in[6];
    float*       out      = (float*)d_out;

    // ---- workspace layout ----
    char* base = (char*)d_ws;
    size_t off = 0;
    auto alloc = [&](size_t bytes) -> char* {
        char* p = base + off;
        off = (off + bytes + 255) & ~(size_t)255;
        return p;
    };
    int*    cntArr  = (int*)   alloc((size_t)SCAN_N * sizeof(int));
    int*    baseArr = (int*)   alloc((size_t)SCAN_N * sizeof(int));
    int*    blksum  = (int*)   alloc((size_t)(NBLK_S + 1) * sizeof(int));
    int*    rowptr  = (int*)   alloc((size_t)(N_NODES + 1) * sizeof(int));
    int*    gcur    = (int*)   alloc((size_t)64 * sizeof(int));
    int2*   ebuf    = (int2*)  alloc((size_t)NNZ * sizeof(int2));
    int2*   ebuf2   = (int2*)  alloc((size_t)NNZ * sizeof(int2));
    int2*   packed  = (int2*)  alloc((size_t)PACKED_CAP * sizeof(int2));
    int*    perm    = (int*)   alloc((size_t)N_NODES * sizeof(int));
    int*    tw      = (int*)   alloc((size_t)NWAVES * sizeof(int));
    int*    twb     = (int*)   alloc((size_t)NWAVES * sizeof(int));
    ushort* xb      = (ushort*)alloc((size_t)N_NODES * DIM * sizeof(ushort));
    ushort* buf0    = (ushort*)alloc((size_t)N_NODES * DIM * sizeof(ushort));
    ushort* buf1    = (ushort*)alloc((size_t)N_NODES * DIM * sizeof(ushort));

    const int TB = 256;

    // ---- count + convert (fused independent work) ----
    count_convert_kernel<<<NWG + CVB, TB, 0, stream>>>(
        rows, cntArr, user_emb, item_emb, xb);

    // ---- scan (blksum stays separate; consumers add it inline) ----
    scan_block_kernel<<<NBLK_S, SCAN_B, 0, stream>>>(cntArr, baseArr, blksum, SCAN_N);
    scan_top_kernel<<<1, SCAN_B, 0, stream>>>(blksum, NBLK_S, rowptr, gcur);

    // ---- scatter + buildpack ----
    scatter_lds_kernel<<<NWG, TB, 0, stream>>>(rows, cols, vals, baseArr, blksum, ebuf);
    buildpack_kernel<<<NBUCK, TB, 0, stream>>>(
        baseArr, blksum, ebuf, ebuf2, rowptr, perm, tw, twb, packed, gcur);

    // ---- propagation ----
    const int spmmBlocks = (NWAVES * 64 + TB - 1) / TB;
    spmm8p_kernel<<<spmmBlocks, TB, 0, stream>>>(
        perm, twb, tw, (const long long*)packed, xb, buf0);
    spmm8p_kernel<<<spmmBlocks, TB, 0, stream>>>(
        perm, twb, tw, (const long long*)packed, buf0, buf1);

    // ---- fused layer-3 + output ----
    const int boBlocks = (BATCH / 4 * 64 + TB - 1) / TB;
    batch_out_kernel<<<boBlocks, TB, 0, stream>>>(
        user_idx, item_idx, rowptr, ebuf2, buf1,
        user_emb, item_emb, buf0, buf1, out);
}